// Round 1
// baseline (354.713 us; speedup 1.0000x reference)
//
#include <hip/hip_runtime.h>

#define HW    4096      // 64*64
#define CIN   256
#define COUT  512
#define NSPE  64500
#define NFAM  510
#define NORD  100
#define NOUT  65110     // 64500+510+100

// ---------------- QKV 1x1-conv GEMM (fp32, LDS-tiled) ----------------
// out[o,p] = bias[o] + sum_c W[o,c] * x[c,p]    (one batch)
// tile: 64 o x 64 p, K-chunk 16; 256 threads, 4x4 micro-tile
__global__ __launch_bounds__(256) void qkv_kernel(
    const float* __restrict__ x,
    const float* __restrict__ wq, const float* __restrict__ bq,
    const float* __restrict__ wk, const float* __restrict__ bk,
    const float* __restrict__ wv, const float* __restrict__ bv,
    float* __restrict__ qout, float* __restrict__ kout, float* __restrict__ vout)
{
    const int mat = blockIdx.z;
    const float* __restrict__ W  = (mat == 0) ? wq : (mat == 1) ? wk : wv;
    const float* __restrict__ bs = (mat == 0) ? bq : (mat == 1) ? bk : bv;
    float* __restrict__ out      = (mat == 0) ? qout : (mat == 1) ? kout : vout;

    const int o0 = blockIdx.y * 64;
    const int p0 = blockIdx.x * 64;
    const int tid = threadIdx.x;
    const int tx = tid & 15;        // p group (4 p each)
    const int ty = tid >> 4;        // o group (4 o each)

    __shared__ float Ws[16][64];    // [c][o]
    __shared__ float Xs[16][64];    // [c][p]

    float acc[4][4] = {};

    for (int c0 = 0; c0 < CIN; c0 += 16) {
        // load W tile: 64 o x 16 c  -> Ws[c][o]
        #pragma unroll
        for (int e = tid; e < 64 * 16; e += 256) {
            int o = e >> 4, c = e & 15;
            Ws[c][o] = W[(o0 + o) * CIN + c0 + c];
        }
        // load X tile: 16 c x 64 p -> Xs[c][p] (coalesced)
        #pragma unroll
        for (int e = tid; e < 16 * 64; e += 256) {
            int c = e >> 6, p = e & 63;
            Xs[c][p] = x[(c0 + c) * HW + p0 + p];
        }
        __syncthreads();
        #pragma unroll
        for (int cc = 0; cc < 16; ++cc) {
            float4 wv4 = reinterpret_cast<const float4*>(&Ws[cc][0])[ty];
            float4 xv4 = reinterpret_cast<const float4*>(&Xs[cc][0])[tx];
            const float wr[4] = {wv4.x, wv4.y, wv4.z, wv4.w};
            const float xr[4] = {xv4.x, xv4.y, xv4.z, xv4.w};
            #pragma unroll
            for (int i = 0; i < 4; ++i)
                #pragma unroll
                for (int j = 0; j < 4; ++j)
                    acc[i][j] += wr[i] * xr[j];
        }
        __syncthreads();
    }

    #pragma unroll
    for (int i = 0; i < 4; ++i) {
        int o = o0 + ty * 4 + i;
        float b = bs[o];
        float4 r = make_float4(acc[i][0] + b, acc[i][1] + b,
                               acc[i][2] + b, acc[i][3] + b);
        *reinterpret_cast<float4*>(&out[o * HW + p0 + tx * 4]) = r;
    }
}

// ------------- attention (9-way per-channel softmax) + relu + pool -------------
// one block: one channel c, 4 h-rows x 64 w; reduces relu(out) into pooled[c]
__global__ __launch_bounds__(256) void attn_pool_kernel(
    const float* __restrict__ q, const float* __restrict__ k,
    const float* __restrict__ v,
    const float* __restrict__ rel_h, const float* __restrict__ rel_w,
    float* __restrict__ pooled)   // [COUT] for this batch
{
    const int c   = blockIdx.y;
    const int h0  = blockIdx.x * 4;
    const int tid = threadIdx.x;
    const int w   = tid & 63;
    const int h   = h0 + (tid >> 6);

    const float* __restrict__ qc = q + c * HW;
    const float* __restrict__ kc = k + c * HW;
    const float* __restrict__ vc = v + c * HW;

    const float qv = qc[h * 64 + w];

    float s[9], vv[9];
    #pragma unroll
    for (int t = 0; t < 9; ++t) {
        const int kh = t / 3, kw = t % 3;
        const int y = h + kh - 1, xw = w + kw - 1;
        const bool valid = ((unsigned)y < 64u) && ((unsigned)xw < 64u);
        const float kval = valid ? kc[y * 64 + xw] : 0.f;
        vv[t]            = valid ? vc[y * 64 + xw] : 0.f;
        const float rel = (c < 256) ? rel_h[c * 3 + kh] : rel_w[(c - 256) * 3 + kw];
        s[t] = qv * (kval + rel);   // padded positions: k=0 but rel still added (per reference)
    }
    float m = s[0];
    #pragma unroll
    for (int t = 1; t < 9; ++t) m = fmaxf(m, s[t]);
    float den = 0.f, num = 0.f;
    #pragma unroll
    for (int t = 0; t < 9; ++t) {
        float e = __expf(s[t] - m);
        den += e;
        num += e * vv[t];
    }
    float r = fmaxf(num / den, 0.f);

    // block reduction: wave shuffle then cross-wave via LDS
    #pragma unroll
    for (int off = 32; off; off >>= 1) r += __shfl_down(r, off);
    __shared__ float red[4];
    if ((tid & 63) == 0) red[tid >> 6] = r;
    __syncthreads();
    if (tid == 0)
        atomicAdd(&pooled[c], (red[0] + red[1] + red[2] + red[3]) * (1.f / 4096.f));
}

// ------------- classifier heads: out[b,j] = pooled[b,:] . Wrow[j,:] + bias -------------
// wave-per-row; lane l owns elements [8l, 8l+8); pooled slice kept in registers
__global__ __launch_bounds__(256) void heads_kernel(
    const float* __restrict__ pooled,    // [4][COUT], already /4096
    const float* __restrict__ w_sp, const float* __restrict__ b_sp,
    const float* __restrict__ w_fa, const float* __restrict__ b_fa,
    const float* __restrict__ w_or, const float* __restrict__ b_or,
    float* __restrict__ out)             // [4][NOUT]
{
    const int lane   = threadIdx.x & 63;
    const int wave   = blockIdx.x * (blockDim.x >> 6) + (threadIdx.x >> 6);
    const int nwaves = gridDim.x * (blockDim.x >> 6);

    float pr[4][8];
    #pragma unroll
    for (int b = 0; b < 4; ++b)
        #pragma unroll
        for (int e = 0; e < 8; ++e)
            pr[b][e] = pooled[b * COUT + lane * 8 + e];

    for (int j = wave; j < NOUT; j += nwaves) {
        const float* __restrict__ wrow;
        float bias;
        if (j < NSPE)            { wrow = w_sp + (size_t)j * COUT;          bias = b_sp[j]; }
        else if (j < NSPE + NFAM){ wrow = w_fa + (size_t)(j - NSPE) * COUT; bias = b_fa[j - NSPE]; }
        else                     { wrow = w_or + (size_t)(j - NSPE - NFAM) * COUT; bias = b_or[j - NSPE - NFAM]; }

        const float4 w0 = reinterpret_cast<const float4*>(wrow)[lane * 2 + 0];
        const float4 w1 = reinterpret_cast<const float4*>(wrow)[lane * 2 + 1];
        const float we[8] = {w0.x, w0.y, w0.z, w0.w, w1.x, w1.y, w1.z, w1.w};

        float a0 = 0.f, a1 = 0.f, a2 = 0.f, a3 = 0.f;
        #pragma unroll
        for (int e = 0; e < 8; ++e) {
            a0 += we[e] * pr[0][e];
            a1 += we[e] * pr[1][e];
            a2 += we[e] * pr[2][e];
            a3 += we[e] * pr[3][e];
        }
        #pragma unroll
        for (int off = 32; off; off >>= 1) {
            a0 += __shfl_down(a0, off);
            a1 += __shfl_down(a1, off);
            a2 += __shfl_down(a2, off);
            a3 += __shfl_down(a3, off);
        }
        if (lane == 0) {
            out[0 * NOUT + j] = a0 + bias;
            out[1 * NOUT + j] = a1 + bias;
            out[2 * NOUT + j] = a2 + bias;
            out[3 * NOUT + j] = a3 + bias;
        }
    }
}

extern "C" void kernel_launch(void* const* d_in, const int* in_sizes, int n_in,
                              void* d_out, int out_size, void* d_ws, size_t ws_size,
                              hipStream_t stream) {
    const float* x     = (const float*)d_in[0];
    const float* wq    = (const float*)d_in[1];
    const float* bq    = (const float*)d_in[2];
    const float* wk    = (const float*)d_in[3];
    const float* bk    = (const float*)d_in[4];
    const float* wv    = (const float*)d_in[5];
    const float* bv    = (const float*)d_in[6];
    const float* rel_h = (const float*)d_in[7];
    const float* rel_w = (const float*)d_in[8];
    const float* w_sp  = (const float*)d_in[9];
    const float* b_sp  = (const float*)d_in[10];
    const float* w_fa  = (const float*)d_in[11];
    const float* b_fa  = (const float*)d_in[12];
    const float* w_or  = (const float*)d_in[13];
    const float* b_or  = (const float*)d_in[14];
    float* out = (float*)d_out;

    // ws layout (per-batch reuse): q | k | v | pooled[4*512]
    float* qb     = (float*)d_ws;
    float* kb     = qb + (size_t)COUT * HW;
    float* vb     = kb + (size_t)COUT * HW;
    float* pooled = vb + (size_t)COUT * HW;

    hipMemsetAsync(pooled, 0, 4 * COUT * sizeof(float), stream);

    for (int b = 0; b < 4; ++b) {
        const float* xb = x + (size_t)b * CIN * HW;
        qkv_kernel<<<dim3(HW / 64, COUT / 64, 3), 256, 0, stream>>>(
            xb, wq, bq, wk, bk, wv, bv, qb, kb, vb);
        attn_pool_kernel<<<dim3(16, COUT), 256, 0, stream>>>(
            qb, kb, vb, rel_h, rel_w, pooled + b * COUT);
    }
    heads_kernel<<<dim3(1024), 256, 0, stream>>>(
        pooled, w_sp, b_sp, w_fa, b_fa, w_or, b_or, out);
}

// Round 2
// 168.346 us; speedup vs baseline: 2.1070x; 2.1070x over previous
//
#include <hip/hip_runtime.h>
#include <stdint.h>

#define HW    4096      // 64*64
#define CIN   256
#define COUT  512
#define NSPE  64500
#define NFAM  510
#define NORD  100
#define NOUT  65110     // 64500+510+100

typedef __attribute__((ext_vector_type(8))) short bf16x8;
typedef __attribute__((ext_vector_type(4))) float f32x4;
typedef __attribute__((address_space(3))) uint32_t lds_u32;
typedef __attribute__((address_space(1))) const uint32_t glob_u32;

__device__ __forceinline__ short f32_to_bf16(float f) {
    uint32_t u = __float_as_uint(f);
    u += 0x7fffu + ((u >> 16) & 1u);   // RNE
    return (short)(u >> 16);
}
__device__ __forceinline__ float bf16_to_f32(unsigned short s) {
    return __uint_as_float(((uint32_t)s) << 16);
}

// Tile layout: [128 rows][32 k] bf16, element (row,k) stored at
//   row*32 + ((k>>3 ^ ((row>>1)&3))<<3) + (k&7)     (slot-XOR swizzle)

// ---- convert W [mat][512][256] fp32 -> tiled-swizzled bf16 ----
__global__ __launch_bounds__(256) void convert_w_kernel(
    const float* __restrict__ wq, const float* __restrict__ wk,
    const float* __restrict__ wv, short* __restrict__ Wt)
{
    const int kt = blockIdx.x, mt = blockIdx.y, mat = blockIdx.z;
    const float* __restrict__ W = (mat == 0) ? wq : (mat == 1) ? wk : wv;
    const int t = threadIdx.x;
    const int m = t >> 1;                       // row in tile (2 threads/row)
    short* out = Wt + (((size_t)(mat * 4 + mt) * 8 + kt) << 12);

    union { short s[16]; int4 v[2]; } pk;
    #pragma unroll
    for (int j = 0; j < 16; ++j) {
        int e  = t * 16 + j;
        int sp = (e >> 3) & 3;
        int i  = e & 7;
        int k  = ((sp ^ ((m >> 1) & 3)) << 3) + i;
        pk.s[j] = f32_to_bf16(W[(size_t)(mt * 128 + m) * CIN + kt * 32 + k]);
    }
    int4* dst = (int4*)(out + t * 16);
    dst[0] = pk.v[0];
    dst[1] = pk.v[1];
}

// ---- convert x [b][256][4096] fp32 -> Xt tiles [b][nt][kt][128 n][32 k] bf16 ----
__global__ __launch_bounds__(256) void convert_x_kernel(
    const float* __restrict__ x, short* __restrict__ Xt)
{
    const int kt = blockIdx.x, nt = blockIdx.y, b = blockIdx.z;
    const int t = threadIdx.x;
    __shared__ float lds[32][128];

    // phase 1: coalesced read of [32 c][128 p] region
    #pragma unroll
    for (int j = 0; j < 16; ++j) {
        int idx = j * 256 + t;
        int c = idx >> 7, p = idx & 127;
        lds[c][p] = x[((size_t)b * CIN + kt * 32 + c) * HW + nt * 128 + p];
    }
    __syncthreads();

    // phase 2: transposed, swizzled, bf16-packed coalesced write
    const int n = t >> 1;
    short* out = Xt + (((size_t)(b * 32 + nt) * 8 + kt) << 12);
    union { short s[16]; int4 v[2]; } pk;
    #pragma unroll
    for (int j = 0; j < 16; ++j) {
        int e  = t * 16 + j;
        int sp = (e >> 3) & 3;
        int i  = e & 7;
        int k  = ((sp ^ ((n >> 1) & 3)) << 3) + i;
        pk.s[j] = f32_to_bf16(lds[k][n]);
    }
    int4* dst = (int4*)(out + t * 16);
    dst[0] = pk.v[0];
    dst[1] = pk.v[1];
}

// ---- QKV GEMM: out[mat,b][m][n] = bias[m] + sum_k W[m][k] X[b][k][n], bf16 MFMA ----
// block: 128m x 128n tile, 4 waves 2x2 (each 64x64), BK=32, 8 K-steps
__global__ __launch_bounds__(256) void qkv_mfma_kernel(
    const short* __restrict__ Wt, const short* __restrict__ Xt,
    const float* __restrict__ bq, const float* __restrict__ bk,
    const float* __restrict__ bv, short* __restrict__ qkv)
{
    const int nt = blockIdx.x, mt = blockIdx.y, z = blockIdx.z;
    const int mat = z >> 2, b = z & 3;
    const short* At = Wt + (((size_t)(mat * 4 + mt) * 8) << 12);
    const short* Bt = Xt + (((size_t)(b * 32 + nt) * 8) << 12);

    __shared__ __align__(16) short As[4096];
    __shared__ __align__(16) short Bs[4096];

    const int tid = threadIdx.x, lane = tid & 63, wid = tid >> 6;
    const int wm = wid >> 1, wn = wid & 1;
    const int l15 = lane & 15, sl = lane >> 4;
    const int sw = ((sl ^ ((l15 >> 1) & 3)) << 3);

    f32x4 acc[4][4] = {};

    for (int kt = 0; kt < 8; ++kt) {
        // stage 16KB (A 8KB + B 8KB) via global_load_lds; wave wid does 4 chunks
        #pragma unroll
        for (int j = 0; j < 4; ++j) {
            int li = wid * 4 + j;
            if (li < 8)
                __builtin_amdgcn_global_load_lds(
                    (glob_u32*)(At + kt * 4096 + li * 512 + lane * 8),
                    (lds_u32*)(As + li * 512), 16, 0, 0);
            else
                __builtin_amdgcn_global_load_lds(
                    (glob_u32*)(Bt + kt * 4096 + (li - 8) * 512 + lane * 8),
                    (lds_u32*)(Bs + (li - 8) * 512), 16, 0, 0);
        }
        __syncthreads();

        bf16x8 a[4], bb[4];
        #pragma unroll
        for (int f = 0; f < 4; ++f) {
            int ra = wm * 64 + f * 16 + l15;
            a[f]  = *(const bf16x8*)(As + ra * 32 + sw);
            int rb = wn * 64 + f * 16 + l15;
            bb[f] = *(const bf16x8*)(Bs + rb * 32 + sw);
        }
        #pragma unroll
        for (int mf = 0; mf < 4; ++mf)
            #pragma unroll
            for (int nf = 0; nf < 4; ++nf)
                acc[mf][nf] = __builtin_amdgcn_mfma_f32_16x16x32_bf16(
                    a[mf], bb[nf], acc[mf][nf], 0, 0, 0);
        __syncthreads();
    }

    // epilogue: +bias, cvt bf16, store
    const float* bias = (mat == 0) ? bq : (mat == 1) ? bk : bv;
    short* out = qkv + (((size_t)(b * 3 + mat) * COUT + mt * 128) * HW) + nt * 128;
    const int col = lane & 15, g = lane >> 4;
    #pragma unroll
    for (int mf = 0; mf < 4; ++mf) {
        #pragma unroll
        for (int nf = 0; nf < 4; ++nf) {
            #pragma unroll
            for (int r = 0; r < 4; ++r) {
                int m = wm * 64 + mf * 16 + g * 4 + r;
                int n = wn * 64 + nf * 16 + col;
                float val = acc[mf][nf][r] + bias[mt * 128 + m];
                out[(size_t)m * HW + n] = f32_to_bf16(val);
            }
        }
    }
}

// ---- attention (9-way per-channel softmax) + relu + pool, bf16 in ----
__global__ __launch_bounds__(256) void attn_pool_kernel(
    const unsigned short* __restrict__ qkv,
    const float* __restrict__ rel_h, const float* __restrict__ rel_w,
    float* __restrict__ pooled)   // [4][COUT]
{
    const int c  = blockIdx.y;
    const int b  = blockIdx.z;
    const int h0 = blockIdx.x * 4;
    const int tid = threadIdx.x;
    const int w = tid & 63;
    const int h = h0 + (tid >> 6);

    const unsigned short* qc = qkv + ((size_t)(b * 3 + 0) * COUT + c) * HW;
    const unsigned short* kc = qkv + ((size_t)(b * 3 + 1) * COUT + c) * HW;
    const unsigned short* vc = qkv + ((size_t)(b * 3 + 2) * COUT + c) * HW;

    const float qv = bf16_to_f32(qc[h * 64 + w]);

    float s[9], vv[9];
    #pragma unroll
    for (int t = 0; t < 9; ++t) {
        const int kh = t / 3, kw = t % 3;
        const int y = h + kh - 1, xw = w + kw - 1;
        const bool valid = ((unsigned)y < 64u) && ((unsigned)xw < 64u);
        const float kval = valid ? bf16_to_f32(kc[y * 64 + xw]) : 0.f;
        vv[t]            = valid ? bf16_to_f32(vc[y * 64 + xw]) : 0.f;
        const float rel = (c < 256) ? rel_h[c * 3 + kh] : rel_w[(c - 256) * 3 + kw];
        s[t] = qv * (kval + rel);
    }
    float m = s[0];
    #pragma unroll
    for (int t = 1; t < 9; ++t) m = fmaxf(m, s[t]);
    float den = 0.f, num = 0.f;
    #pragma unroll
    for (int t = 0; t < 9; ++t) {
        float e = __expf(s[t] - m);
        den += e;
        num += e * vv[t];
    }
    float r = fmaxf(num / den, 0.f);

    #pragma unroll
    for (int off = 32; off; off >>= 1) r += __shfl_down(r, off);
    __shared__ float red[4];
    if ((tid & 63) == 0) red[tid >> 6] = r;
    __syncthreads();
    if (tid == 0)
        atomicAdd(&pooled[b * COUT + c],
                  (red[0] + red[1] + red[2] + red[3]) * (1.f / 4096.f));
}

// ---- classifier heads ----
__global__ __launch_bounds__(256) void heads_kernel(
    const float* __restrict__ pooled,    // [4][COUT]
    const float* __restrict__ w_sp, const float* __restrict__ b_sp,
    const float* __restrict__ w_fa, const float* __restrict__ b_fa,
    const float* __restrict__ w_or, const float* __restrict__ b_or,
    float* __restrict__ out)             // [4][NOUT]
{
    const int lane   = threadIdx.x & 63;
    const int wave   = blockIdx.x * (blockDim.x >> 6) + (threadIdx.x >> 6);
    const int nwaves = gridDim.x * (blockDim.x >> 6);

    float pr[4][8];
    #pragma unroll
    for (int b = 0; b < 4; ++b)
        #pragma unroll
        for (int e = 0; e < 8; ++e)
            pr[b][e] = pooled[b * COUT + lane * 8 + e];

    for (int j = wave; j < NOUT; j += nwaves) {
        const float* __restrict__ wrow;
        float bias;
        if (j < NSPE)            { wrow = w_sp + (size_t)j * COUT;          bias = b_sp[j]; }
        else if (j < NSPE + NFAM){ wrow = w_fa + (size_t)(j - NSPE) * COUT; bias = b_fa[j - NSPE]; }
        else                     { wrow = w_or + (size_t)(j - NSPE - NFAM) * COUT; bias = b_or[j - NSPE - NFAM]; }

        const float4 w0 = reinterpret_cast<const float4*>(wrow)[lane * 2 + 0];
        const float4 w1 = reinterpret_cast<const float4*>(wrow)[lane * 2 + 1];
        const float we[8] = {w0.x, w0.y, w0.z, w0.w, w1.x, w1.y, w1.z, w1.w};

        float a0 = 0.f, a1 = 0.f, a2 = 0.f, a3 = 0.f;
        #pragma unroll
        for (int e = 0; e < 8; ++e) {
            a0 += we[e] * pr[0][e];
            a1 += we[e] * pr[1][e];
            a2 += we[e] * pr[2][e];
            a3 += we[e] * pr[3][e];
        }
        #pragma unroll
        for (int off = 32; off; off >>= 1) {
            a0 += __shfl_down(a0, off);
            a1 += __shfl_down(a1, off);
            a2 += __shfl_down(a2, off);
            a3 += __shfl_down(a3, off);
        }
        if (lane == 0) {
            out[0 * NOUT + j] = a0 + bias;
            out[1 * NOUT + j] = a1 + bias;
            out[2 * NOUT + j] = a2 + bias;
            out[3 * NOUT + j] = a3 + bias;
        }
    }
}

extern "C" void kernel_launch(void* const* d_in, const int* in_sizes, int n_in,
                              void* d_out, int out_size, void* d_ws, size_t ws_size,
                              hipStream_t stream) {
    const float* x     = (const float*)d_in[0];
    const float* wq    = (const float*)d_in[1];
    const float* bq    = (const float*)d_in[2];
    const float* wk    = (const float*)d_in[3];
    const float* bk    = (const float*)d_in[4];
    const float* wv    = (const float*)d_in[5];
    const float* bv    = (const float*)d_in[6];
    const float* rel_h = (const float*)d_in[7];
    const float* rel_w = (const float*)d_in[8];
    const float* w_sp  = (const float*)d_in[9];
    const float* b_sp  = (const float*)d_in[10];
    const float* w_fa  = (const float*)d_in[11];
    const float* b_fa  = (const float*)d_in[12];
    const float* w_or  = (const float*)d_in[13];
    const float* b_or  = (const float*)d_in[14];
    float* out = (float*)d_out;

    // ws: Wt bf16 | Xt bf16 | qkv bf16 | pooled f32
    short* Wt  = (short*)d_ws;                       // 3*512*256   = 393216
    short* Xt  = Wt + 393216;                        // 4*256*4096  = 4194304
    short* qkv = Xt + 4194304;                       // 4*3*512*4096= 25165824
    float* pooled = (float*)(qkv + 25165824);        // 4*512

    hipMemsetAsync(pooled, 0, 4 * COUT * sizeof(float), stream);

    convert_w_kernel<<<dim3(8, 4, 3), 256, 0, stream>>>(wq, wk, wv, Wt);
    convert_x_kernel<<<dim3(8, 32, 4), 256, 0, stream>>>(x, Xt);
    qkv_mfma_kernel<<<dim3(32, 4, 12), 256, 0, stream>>>(Wt, Xt, bq, bk, bv, qkv);
    attn_pool_kernel<<<dim3(16, COUT, 4), 256, 0, stream>>>(
        (const unsigned short*)qkv, rel_h, rel_w, pooled);
    heads_kernel<<<dim3(1024), 256, 0, stream>>>(
        pooled, w_sp, b_sp, w_fa, b_fa, w_or, b_or, out);
}

// Round 3
// 86.394 us; speedup vs baseline: 4.1058x; 1.9486x over previous
//
#include <hip/hip_runtime.h>
#include <stdint.h>

#define HW    4096      // 64*64
#define CIN   256
#define COUT  512
#define NSPE  64500
#define NFAM  510
#define NORD  100
#define NOUT  65110     // 64500+510+100

typedef __attribute__((ext_vector_type(8))) short bf16x8;
typedef __attribute__((ext_vector_type(4))) float f32x4;
typedef __attribute__((address_space(3))) uint32_t lds_u32;
typedef __attribute__((address_space(1))) const uint32_t glob_u32;

__device__ __forceinline__ short f32_to_bf16(float f) {
    uint32_t u = __float_as_uint(f);
    u += 0x7fffu + ((u >> 16) & 1u);   // RNE
    return (short)(u >> 16);
}
__device__ __forceinline__ float bf16_to_f32(unsigned short s) {
    return __uint_as_float(((uint32_t)s) << 16);
}

// Tile layout: [128 rows][32 k] bf16, element (row,k) stored at
//   row*32 + ((k>>3 ^ ((row>>1)&3))<<3) + (k&7)     (slot-XOR swizzle)

// ---- convert W [mat][512][256] fp32 -> tiled-swizzled bf16 ----
__global__ __launch_bounds__(256) void convert_w_kernel(
    const float* __restrict__ wq, const float* __restrict__ wk,
    const float* __restrict__ wv, short* __restrict__ Wt)
{
    const int kt = blockIdx.x, mt = blockIdx.y, mat = blockIdx.z;
    const float* __restrict__ W = (mat == 0) ? wq : (mat == 1) ? wk : wv;
    const int t = threadIdx.x;
    const int m = t >> 1;                       // row in tile (2 threads/row)
    short* out = Wt + (((size_t)(mat * 4 + mt) * 8 + kt) << 12);

    union { short s[16]; int4 v[2]; } pk;
    #pragma unroll
    for (int j = 0; j < 16; ++j) {
        int e  = t * 16 + j;
        int sp = (e >> 3) & 3;
        int i  = e & 7;
        int k  = ((sp ^ ((m >> 1) & 3)) << 3) + i;
        pk.s[j] = f32_to_bf16(W[(size_t)(mt * 128 + m) * CIN + kt * 32 + k]);
    }
    int4* dst = (int4*)(out + t * 16);
    dst[0] = pk.v[0];
    dst[1] = pk.v[1];
}

// ---- convert x [b][256][4096] fp32 -> Xt tiles [b][nt][kt][128 n][32 k] bf16 ----
__global__ __launch_bounds__(256) void convert_x_kernel(
    const float* __restrict__ x, short* __restrict__ Xt)
{
    const int kt = blockIdx.x, nt = blockIdx.y, b = blockIdx.z;
    const int t = threadIdx.x;
    __shared__ float lds[32][128];

    // phase 1: coalesced read of [32 c][128 p] region
    #pragma unroll
    for (int j = 0; j < 16; ++j) {
        int idx = j * 256 + t;
        int c = idx >> 7, p = idx & 127;
        lds[c][p] = x[((size_t)b * CIN + kt * 32 + c) * HW + nt * 128 + p];
    }
    __syncthreads();

    // phase 2: transposed, swizzled, bf16-packed coalesced write
    const int n = t >> 1;
    short* out = Xt + (((size_t)(b * 32 + nt) * 8 + kt) << 12);
    union { short s[16]; int4 v[2]; } pk;
    #pragma unroll
    for (int j = 0; j < 16; ++j) {
        int e  = t * 16 + j;
        int sp = (e >> 3) & 3;
        int i  = e & 7;
        int k  = ((sp ^ ((n >> 1) & 3)) << 3) + i;
        pk.s[j] = f32_to_bf16(lds[k][n]);
    }
    int4* dst = (int4*)(out + t * 16);
    dst[0] = pk.v[0];
    dst[1] = pk.v[1];
}

// ---- QKV GEMM: out[mat,b][m][n] = bias[m] + sum_k W[m][k] X[b][k][n], bf16 MFMA ----
__global__ __launch_bounds__(256) void qkv_mfma_kernel(
    const short* __restrict__ Wt, const short* __restrict__ Xt,
    const float* __restrict__ bq, const float* __restrict__ bk,
    const float* __restrict__ bv, short* __restrict__ qkv)
{
    const int nt = blockIdx.x, mt = blockIdx.y, z = blockIdx.z;
    const int mat = z >> 2, b = z & 3;
    const short* At = Wt + (((size_t)(mat * 4 + mt) * 8) << 12);
    const short* Bt = Xt + (((size_t)(b * 32 + nt) * 8) << 12);

    __shared__ __align__(16) short As[4096];
    __shared__ __align__(16) short Bs[4096];

    const int tid = threadIdx.x, lane = tid & 63, wid = tid >> 6;
    const int wm = wid >> 1, wn = wid & 1;
    const int l15 = lane & 15, sl = lane >> 4;
    const int sw = ((sl ^ ((l15 >> 1) & 3)) << 3);

    f32x4 acc[4][4] = {};

    for (int kt = 0; kt < 8; ++kt) {
        #pragma unroll
        for (int j = 0; j < 4; ++j) {
            int li = wid * 4 + j;
            if (li < 8)
                __builtin_amdgcn_global_load_lds(
                    (glob_u32*)(At + kt * 4096 + li * 512 + lane * 8),
                    (lds_u32*)(As + li * 512), 16, 0, 0);
            else
                __builtin_amdgcn_global_load_lds(
                    (glob_u32*)(Bt + kt * 4096 + (li - 8) * 512 + lane * 8),
                    (lds_u32*)(Bs + (li - 8) * 512), 16, 0, 0);
        }
        __syncthreads();

        bf16x8 a[4], bb[4];
        #pragma unroll
        for (int f = 0; f < 4; ++f) {
            int ra = wm * 64 + f * 16 + l15;
            a[f]  = *(const bf16x8*)(As + ra * 32 + sw);
            int rb = wn * 64 + f * 16 + l15;
            bb[f] = *(const bf16x8*)(Bs + rb * 32 + sw);
        }
        #pragma unroll
        for (int mf = 0; mf < 4; ++mf)
            #pragma unroll
            for (int nf = 0; nf < 4; ++nf)
                acc[mf][nf] = __builtin_amdgcn_mfma_f32_16x16x32_bf16(
                    a[mf], bb[nf], acc[mf][nf], 0, 0, 0);
        __syncthreads();
    }

    const float* bias = (mat == 0) ? bq : (mat == 1) ? bk : bv;
    short* out = qkv + (((size_t)(b * 3 + mat) * COUT + mt * 128) * HW) + nt * 128;
    const int col = lane & 15, g = lane >> 4;
    #pragma unroll
    for (int mf = 0; mf < 4; ++mf) {
        #pragma unroll
        for (int nf = 0; nf < 4; ++nf) {
            #pragma unroll
            for (int r = 0; r < 4; ++r) {
                int m = wm * 64 + mf * 16 + g * 4 + r;
                int n = wn * 64 + nf * 16 + col;
                float val = acc[mf][nf][r] + bias[mt * 128 + m];
                out[(size_t)m * HW + n] = f32_to_bf16(val);
            }
        }
    }
}

// ---- attention + relu + pool: one block per (channel, batch) ----
// k,v staged in LDS (stride 72 u16 -> 2-way-max bank aliasing); each thread
// owns one quarter-row (16 px); softmax fully unrolled, static indices.
__global__ __launch_bounds__(256) void attn_pool_kernel(
    const unsigned short* __restrict__ qkv,
    const float* __restrict__ rel_h, const float* __restrict__ rel_w,
    float* __restrict__ pooled)   // [4][COUT]
{
    const int c = blockIdx.x;
    const int b = blockIdx.y;
    const int tid = threadIdx.x;
    const int h  = tid >> 2;            // 0..63
    const int w0 = (tid & 3) * 16;      // 0,16,32,48

    const unsigned short* qc = qkv + ((size_t)(b * 3 + 0) * COUT + c) * HW;
    const unsigned short* kc = qkv + ((size_t)(b * 3 + 1) * COUT + c) * HW;
    const unsigned short* vc = qkv + ((size_t)(b * 3 + 2) * COUT + c) * HW;

    __shared__ __align__(16) unsigned short kS[64 * 72];
    __shared__ __align__(16) unsigned short vS[64 * 72];

    // stage k,v: 512 int4 chunks each, 2 per thread, 16B-aligned LDS rows
    #pragma unroll
    for (int it = 0; it < 2; ++it) {
        int ch = tid + it * 256;
        int y = ch >> 3, off = (ch & 7) * 8;
        *(int4*)&kS[y * 72 + off] = reinterpret_cast<const int4*>(kc)[ch];
        *(int4*)&vS[y * 72 + off] = reinterpret_cast<const int4*>(vc)[ch];
    }

    // q: 16 px, 2 vectorized loads
    union { unsigned short s[16]; int4 v[2]; } qr;
    qr.v[0] = reinterpret_cast<const int4*>(qc + h * 64 + w0)[0];
    qr.v[1] = reinterpret_cast<const int4*>(qc + h * 64 + w0)[1];
    float qf[16];
    #pragma unroll
    for (int i = 0; i < 16; ++i) qf[i] = bf16_to_f32(qr.s[i]);

    // rel (uniform per block): rel used = (c<256) ? relh[kh] : relw[kw]
    const bool isH = (c < 256);
    float r3[3];
    #pragma unroll
    for (int i = 0; i < 3; ++i)
        r3[i] = isH ? rel_h[c * 3 + i] : rel_w[(c - 256) * 3 + i];

    __syncthreads();

    float total = 0.f;
    #pragma unroll
    for (int i = 0; i < 16; ++i) {
        const int w = w0 + i;
        const float qv = qf[i];
        float s[9], vv9[9];
        #pragma unroll
        for (int kh = 0; kh < 3; ++kh) {
            const int y = h + kh - 1;
            const bool rowok = ((unsigned)y < 64u);
            const int yc = rowok ? y : h;
            #pragma unroll
            for (int kw = 0; kw < 3; ++kw) {
                const int xw = w + kw - 1;
                const bool ok = rowok && ((unsigned)xw < 64u);
                const int xc = ((unsigned)xw < 64u) ? xw : w;
                float kval = bf16_to_f32(kS[yc * 72 + xc]);
                float vval = bf16_to_f32(vS[yc * 72 + xc]);
                kval = ok ? kval : 0.f;
                vval = ok ? vval : 0.f;
                const float rel = isH ? r3[kh] : r3[kw];
                s[kh * 3 + kw]   = qv * (kval + rel);
                vv9[kh * 3 + kw] = vval;
            }
        }
        float m = s[0];
        #pragma unroll
        for (int t = 1; t < 9; ++t) m = fmaxf(m, s[t]);
        float den = 0.f, num = 0.f;
        #pragma unroll
        for (int t = 0; t < 9; ++t) {
            float e = __expf(s[t] - m);
            den += e;
            num += e * vv9[t];
        }
        total += fmaxf(num / den, 0.f);
    }

    // block reduction -> single store (one block per (c,b): no atomics needed)
    #pragma unroll
    for (int off = 32; off; off >>= 1) total += __shfl_down(total, off);
    __shared__ float red[4];
    if ((tid & 63) == 0) red[tid >> 6] = total;
    __syncthreads();
    if (tid == 0)
        pooled[b * COUT + c] = (red[0] + red[1] + red[2] + red[3]) * (1.f / 4096.f);
}

// ---- classifier heads ----
__global__ __launch_bounds__(256) void heads_kernel(
    const float* __restrict__ pooled,    // [4][COUT]
    const float* __restrict__ w_sp, const float* __restrict__ b_sp,
    const float* __restrict__ w_fa, const float* __restrict__ b_fa,
    const float* __restrict__ w_or, const float* __restrict__ b_or,
    float* __restrict__ out)             // [4][NOUT]
{
    const int lane   = threadIdx.x & 63;
    const int wave   = blockIdx.x * (blockDim.x >> 6) + (threadIdx.x >> 6);
    const int nwaves = gridDim.x * (blockDim.x >> 6);

    float pr[4][8];
    #pragma unroll
    for (int b = 0; b < 4; ++b)
        #pragma unroll
        for (int e = 0; e < 8; ++e)
            pr[b][e] = pooled[b * COUT + lane * 8 + e];

    for (int j = wave; j < NOUT; j += nwaves) {
        const float* __restrict__ wrow;
        float bias;
        if (j < NSPE)            { wrow = w_sp + (size_t)j * COUT;          bias = b_sp[j]; }
        else if (j < NSPE + NFAM){ wrow = w_fa + (size_t)(j - NSPE) * COUT; bias = b_fa[j - NSPE]; }
        else                     { wrow = w_or + (size_t)(j - NSPE - NFAM) * COUT; bias = b_or[j - NSPE - NFAM]; }

        const float4 w0 = reinterpret_cast<const float4*>(wrow)[lane * 2 + 0];
        const float4 w1 = reinterpret_cast<const float4*>(wrow)[lane * 2 + 1];
        const float we[8] = {w0.x, w0.y, w0.z, w0.w, w1.x, w1.y, w1.z, w1.w};

        float a0 = 0.f, a1 = 0.f, a2 = 0.f, a3 = 0.f;
        #pragma unroll
        for (int e = 0; e < 8; ++e) {
            a0 += we[e] * pr[0][e];
            a1 += we[e] * pr[1][e];
            a2 += we[e] * pr[2][e];
            a3 += we[e] * pr[3][e];
        }
        #pragma unroll
        for (int off = 32; off; off >>= 1) {
            a0 += __shfl_down(a0, off);
            a1 += __shfl_down(a1, off);
            a2 += __shfl_down(a2, off);
            a3 += __shfl_down(a3, off);
        }
        if (lane == 0) {
            out[0 * NOUT + j] = a0 + bias;
            out[1 * NOUT + j] = a1 + bias;
            out[2 * NOUT + j] = a2 + bias;
            out[3 * NOUT + j] = a3 + bias;
        }
    }
}

extern "C" void kernel_launch(void* const* d_in, const int* in_sizes, int n_in,
                              void* d_out, int out_size, void* d_ws, size_t ws_size,
                              hipStream_t stream) {
    const float* x     = (const float*)d_in[0];
    const float* wq    = (const float*)d_in[1];
    const float* bq    = (const float*)d_in[2];
    const float* wk    = (const float*)d_in[3];
    const float* bk    = (const float*)d_in[4];
    const float* wv    = (const float*)d_in[5];
    const float* bv    = (const float*)d_in[6];
    const float* rel_h = (const float*)d_in[7];
    const float* rel_w = (const float*)d_in[8];
    const float* w_sp  = (const float*)d_in[9];
    const float* b_sp  = (const float*)d_in[10];
    const float* w_fa  = (const float*)d_in[11];
    const float* b_fa  = (const float*)d_in[12];
    const float* w_or  = (const float*)d_in[13];
    const float* b_or  = (const float*)d_in[14];
    float* out = (float*)d_out;

    // ws: Wt bf16 | Xt bf16 | qkv bf16 | pooled f32
    short* Wt  = (short*)d_ws;                       // 3*512*256   = 393216
    short* Xt  = Wt + 393216;                        // 4*256*4096  = 4194304
    short* qkv = Xt + 4194304;                       // 4*3*512*4096= 25165824
    float* pooled = (float*)(qkv + 25165824);        // 4*512

    convert_w_kernel<<<dim3(8, 4, 3), 256, 0, stream>>>(wq, wk, wv, Wt);
    convert_x_kernel<<<dim3(8, 32, 4), 256, 0, stream>>>(x, Xt);
    qkv_mfma_kernel<<<dim3(32, 4, 12), 256, 0, stream>>>(Wt, Xt, bq, bk, bv, qkv);
    attn_pool_kernel<<<dim3(COUT, 4), 256, 0, stream>>>(
        (const unsigned short*)qkv, rel_h, rel_w, pooled);
    heads_kernel<<<dim3(1024), 256, 0, stream>>>(
        pooled, w_sp, b_sp, w_fa, b_fa, w_or, b_or, out);
}

// Round 4
// 84.962 us; speedup vs baseline: 4.1750x; 1.0169x over previous
//
#include <hip/hip_runtime.h>
#include <stdint.h>

#define HW    4096      // 64*64
#define CIN   256
#define COUT  512
#define NSPE  64500
#define NFAM  510
#define NORD  100
#define NOUT  65110     // 64500+510+100

typedef __attribute__((ext_vector_type(8))) short bf16x8;
typedef __attribute__((ext_vector_type(4))) float f32x4;
typedef __attribute__((address_space(3))) uint32_t lds_u32;
typedef __attribute__((address_space(1))) const uint32_t glob_u32;

__device__ __forceinline__ short f32_to_bf16(float f) {
    uint32_t u = __float_as_uint(f);
    u += 0x7fffu + ((u >> 16) & 1u);   // RNE
    return (short)(u >> 16);
}
__device__ __forceinline__ float bf16_to_f32(unsigned short s) {
    return __uint_as_float(((uint32_t)s) << 16);
}

// Tile layout: [128 rows][32 k] bf16, element (row,k) stored at
//   row*32 + ((k>>3 ^ ((row>>1)&3))<<3) + (k&7)     (slot-XOR swizzle)

// ---- convert W [mat][512][256] fp32 -> tiled-swizzled bf16 ----
__global__ __launch_bounds__(256) void convert_w_kernel(
    const float* __restrict__ wq, const float* __restrict__ wk,
    const float* __restrict__ wv, short* __restrict__ Wt)
{
    const int kt = blockIdx.x, mt = blockIdx.y, mat = blockIdx.z;
    const float* __restrict__ W = (mat == 0) ? wq : (mat == 1) ? wk : wv;
    const int t = threadIdx.x;
    const int m = t >> 1;                       // row in tile (2 threads/row)
    short* out = Wt + (((size_t)(mat * 4 + mt) * 8 + kt) << 12);

    union { short s[16]; int4 v[2]; } pk;
    #pragma unroll
    for (int j = 0; j < 16; ++j) {
        int e  = t * 16 + j;
        int sp = (e >> 3) & 3;
        int i  = e & 7;
        int k  = ((sp ^ ((m >> 1) & 3)) << 3) + i;
        pk.s[j] = f32_to_bf16(W[(size_t)(mt * 128 + m) * CIN + kt * 32 + k]);
    }
    int4* dst = (int4*)(out + t * 16);
    dst[0] = pk.v[0];
    dst[1] = pk.v[1];
}

// ---- convert x [b][256][4096] fp32 -> Xt tiles [b][nt][kt][128 n][32 k] bf16 ----
__global__ __launch_bounds__(256) void convert_x_kernel(
    const float* __restrict__ x, short* __restrict__ Xt)
{
    const int kt = blockIdx.x, nt = blockIdx.y, b = blockIdx.z;
    const int t = threadIdx.x;
    __shared__ float lds[32][128];

    #pragma unroll
    for (int j = 0; j < 16; ++j) {
        int idx = j * 256 + t;
        int c = idx >> 7, p = idx & 127;
        lds[c][p] = x[((size_t)b * CIN + kt * 32 + c) * HW + nt * 128 + p];
    }
    __syncthreads();

    const int n = t >> 1;
    short* out = Xt + (((size_t)(b * 32 + nt) * 8 + kt) << 12);
    union { short s[16]; int4 v[2]; } pk;
    #pragma unroll
    for (int j = 0; j < 16; ++j) {
        int e  = t * 16 + j;
        int sp = (e >> 3) & 3;
        int i  = e & 7;
        int k  = ((sp ^ ((n >> 1) & 3)) << 3) + i;
        pk.s[j] = f32_to_bf16(lds[k][n]);
    }
    int4* dst = (int4*)(out + t * 16);
    dst[0] = pk.v[0];
    dst[1] = pk.v[1];
}

// ---- QKV GEMM: double-buffered LDS, bf16 MFMA ----
__global__ __launch_bounds__(256) void qkv_mfma_kernel(
    const short* __restrict__ Wt, const short* __restrict__ Xt,
    const float* __restrict__ bq, const float* __restrict__ bk,
    const float* __restrict__ bv, short* __restrict__ qkv)
{
    const int nt = blockIdx.x, mt = blockIdx.y, z = blockIdx.z;
    const int mat = z >> 2, b = z & 3;
    const short* At = Wt + (((size_t)(mat * 4 + mt) * 8) << 12);
    const short* Bt = Xt + (((size_t)(b * 32 + nt) * 8) << 12);

    __shared__ __align__(16) short As[2][4096];
    __shared__ __align__(16) short Bs[2][4096];

    const int tid = threadIdx.x, lane = tid & 63, wid = tid >> 6;
    const int wm = wid >> 1, wn = wid & 1;
    const int l15 = lane & 15, sl = lane >> 4;
    const int sw = ((sl ^ ((l15 >> 1) & 3)) << 3);

    f32x4 acc[4][4] = {};

#define STAGE(KT, BUF) do {                                                   \
    _Pragma("unroll")                                                         \
    for (int j = 0; j < 4; ++j) {                                             \
        int li = wid * 4 + j;                                                 \
        if (li < 8)                                                           \
            __builtin_amdgcn_global_load_lds(                                 \
                (glob_u32*)(At + (KT) * 4096 + li * 512 + lane * 8),          \
                (lds_u32*)(&As[BUF][li * 512]), 16, 0, 0);                    \
        else                                                                  \
            __builtin_amdgcn_global_load_lds(                                 \
                (glob_u32*)(Bt + (KT) * 4096 + (li - 8) * 512 + lane * 8),    \
                (lds_u32*)(&Bs[BUF][(li - 8) * 512]), 16, 0, 0);              \
    }                                                                         \
} while (0)

    STAGE(0, 0);
    __syncthreads();

    int buf = 0;
    #pragma unroll 2
    for (int kt = 0; kt < 8; ++kt) {
        if (kt < 7) STAGE(kt + 1, buf ^ 1);   // prefetch next tile (flies under MFMA)

        bf16x8 a[4], bb[4];
        #pragma unroll
        for (int f = 0; f < 4; ++f) {
            int ra = wm * 64 + f * 16 + l15;
            a[f]  = *(const bf16x8*)(&As[buf][ra * 32 + sw]);
            int rb = wn * 64 + f * 16 + l15;
            bb[f] = *(const bf16x8*)(&Bs[buf][rb * 32 + sw]);
        }
        #pragma unroll
        for (int mf = 0; mf < 4; ++mf)
            #pragma unroll
            for (int nf = 0; nf < 4; ++nf)
                acc[mf][nf] = __builtin_amdgcn_mfma_f32_16x16x32_bf16(
                    a[mf], bb[nf], acc[mf][nf], 0, 0, 0);
        __syncthreads();   // drains vmcnt (prefetch done) + lgkm before buffer swap
        buf ^= 1;
    }
#undef STAGE

    const float* bias = (mat == 0) ? bq : (mat == 1) ? bk : bv;
    short* out = qkv + (((size_t)(b * 3 + mat) * COUT + mt * 128) * HW) + nt * 128;
    const int col = lane & 15, g = lane >> 4;
    #pragma unroll
    for (int mf = 0; mf < 4; ++mf) {
        #pragma unroll
        for (int nf = 0; nf < 4; ++nf) {
            #pragma unroll
            for (int r = 0; r < 4; ++r) {
                int m = wm * 64 + mf * 16 + g * 4 + r;
                int n = wn * 64 + nf * 16 + col;
                float val = acc[mf][nf][r] + bias[mt * 128 + m];
                out[(size_t)m * HW + n] = f32_to_bf16(val);
            }
        }
    }
}

// ---- attention + relu + pool: one block per (channel, batch) ----
// k,v staged as f32 into zero-PADDED [66][67] LDS images: boundary handling is
// free (k=0,v=0 outside, rel still added -> s = q*rel, matching reference).
// Sliding 3-col register window: 6 ds_read_b32 per pixel, exp2-direct softmax
// (log2e folded into q once), no max-subtraction (|s|<~6, overflow-safe).
__global__ __launch_bounds__(256) void attn_pool_kernel(
    const unsigned short* __restrict__ qkv,
    const float* __restrict__ rel_h, const float* __restrict__ rel_w,
    float* __restrict__ pooled)   // [4][COUT]
{
    const int c = blockIdx.x;
    const int b = blockIdx.y;
    const int tid = threadIdx.x;
    const int h  = tid >> 2;            // 0..63
    const int w0 = (tid & 3) * 16;      // 0,16,32,48

    const unsigned short* qc = qkv + ((size_t)(b * 3 + 0) * COUT + c) * HW;
    const unsigned short* kg = qkv + ((size_t)(b * 3 + 1) * COUT + c) * HW;
    const unsigned short* vg = qkv + ((size_t)(b * 3 + 2) * COUT + c) * HW;

    __shared__ float kS[66 * 67];
    __shared__ float vS[66 * 67];

    // zero the pad border
    if (tid < 67) {
        kS[tid] = 0.f;            vS[tid] = 0.f;             // row -1
        kS[65 * 67 + tid] = 0.f;  vS[65 * 67 + tid] = 0.f;   // row 64
    }
    if (tid < 64) {
        int r0 = (tid + 1) * 67;
        kS[r0] = 0.f;       vS[r0] = 0.f;                    // col -1
        kS[r0 + 65] = 0.f;  vS[r0 + 65] = 0.f;               // col 64
    }

    // stage interior, bf16 -> f32
    #pragma unroll
    for (int it = 0; it < 2; ++it) {
        int ch = tid + it * 256;
        int y = ch >> 3, xs = (ch & 7) * 8;
        union { int4 v; unsigned short s[8]; } ak, av;
        ak.v = reinterpret_cast<const int4*>(kg)[ch];
        av.v = reinterpret_cast<const int4*>(vg)[ch];
        float* kp = &kS[(y + 1) * 67 + xs + 1];
        float* vp = &vS[(y + 1) * 67 + xs + 1];
        #pragma unroll
        for (int e = 0; e < 8; ++e) {
            kp[e] = bf16_to_f32(ak.s[e]);
            vp[e] = bf16_to_f32(av.s[e]);
        }
    }

    // q * log2e (exp2-direct)
    union { unsigned short s[16]; int4 v[2]; } qr;
    qr.v[0] = reinterpret_cast<const int4*>(qc + h * 64 + w0)[0];
    qr.v[1] = reinterpret_cast<const int4*>(qc + h * 64 + w0)[1];
    float qf[16];
    #pragma unroll
    for (int i = 0; i < 16; ++i)
        qf[i] = bf16_to_f32(qr.s[i]) * 1.4426950408889634f;

    // rel table: relv[kh*3+kw] = isH ? rel_h[kh] : rel_w[kw]
    const bool isH = (c < 256);
    float r3[3];
    #pragma unroll
    for (int i = 0; i < 3; ++i)
        r3[i] = isH ? rel_h[c * 3 + i] : rel_w[(c - 256) * 3 + i];
    float relv[9];
    #pragma unroll
    for (int kh = 0; kh < 3; ++kh)
        #pragma unroll
        for (int kw = 0; kw < 3; ++kw)
            relv[kh * 3 + kw] = isH ? r3[kh] : r3[kw];

    __syncthreads();

    const float* krow = &kS[h * 67 + w0];   // window rows h-1..h+1 -> LDS rows h..h+2
    const float* vrow = &vS[h * 67 + w0];

    float kcw[3][3], vcw[3][3];             // [col-slot][row]
    #pragma unroll
    for (int s = 0; s < 2; ++s)
        #pragma unroll
        for (int r = 0; r < 3; ++r) {
            kcw[s][r] = krow[r * 67 + s];
            vcw[s][r] = vrow[r * 67 + s];
        }

    float total = 0.f;
    #pragma unroll
    for (int i = 0; i < 16; ++i) {
        const int s2 = (i + 2) % 3;         // compile-time after unroll
        #pragma unroll
        for (int r = 0; r < 3; ++r) {
            kcw[s2][r] = krow[r * 67 + i + 2];
            vcw[s2][r] = vrow[r * 67 + i + 2];
        }
        const float q2 = qf[i];
        float num = 0.f, den = 0.f;
        #pragma unroll
        for (int r = 0; r < 3; ++r)
            #pragma unroll
            for (int dx = 0; dx < 3; ++dx) {
                const int sl = (i + dx) % 3;
                float e = __builtin_exp2f(q2 * (kcw[sl][r] + relv[r * 3 + dx]));
                den += e;
                num = fmaf(e, vcw[sl][r], num);
            }
        total += fmaxf(num * __builtin_amdgcn_rcpf(den), 0.f);
    }

    #pragma unroll
    for (int off = 32; off; off >>= 1) total += __shfl_down(total, off);
    __shared__ float red[4];
    if ((tid & 63) == 0) red[tid >> 6] = total;
    __syncthreads();
    if (tid == 0)
        pooled[b * COUT + c] = (red[0] + red[1] + red[2] + red[3]) * (1.f / 4096.f);
}

// ---- classifier heads ----
__global__ __launch_bounds__(256) void heads_kernel(
    const float* __restrict__ pooled,    // [4][COUT]
    const float* __restrict__ w_sp, const float* __restrict__ b_sp,
    const float* __restrict__ w_fa, const float* __restrict__ b_fa,
    const float* __restrict__ w_or, const float* __restrict__ b_or,
    float* __restrict__ out)             // [4][NOUT]
{
    const int lane   = threadIdx.x & 63;
    const int wave   = blockIdx.x * (blockDim.x >> 6) + (threadIdx.x >> 6);
    const int nwaves = gridDim.x * (blockDim.x >> 6);

    float pr[4][8];
    #pragma unroll
    for (int b = 0; b < 4; ++b)
        #pragma unroll
        for (int e = 0; e < 8; ++e)
            pr[b][e] = pooled[b * COUT + lane * 8 + e];

    for (int j = wave; j < NOUT; j += nwaves) {
        const float* __restrict__ wrow;
        float bias;
        if (j < NSPE)            { wrow = w_sp + (size_t)j * COUT;          bias = b_sp[j]; }
        else if (j < NSPE + NFAM){ wrow = w_fa + (size_t)(j - NSPE) * COUT; bias = b_fa[j - NSPE]; }
        else                     { wrow = w_or + (size_t)(j - NSPE - NFAM) * COUT; bias = b_or[j - NSPE - NFAM]; }

        const float4 w0 = reinterpret_cast<const float4*>(wrow)[lane * 2 + 0];
        const float4 w1 = reinterpret_cast<const float4*>(wrow)[lane * 2 + 1];
        const float we[8] = {w0.x, w0.y, w0.z, w0.w, w1.x, w1.y, w1.z, w1.w};

        float a0 = 0.f, a1 = 0.f, a2 = 0.f, a3 = 0.f;
        #pragma unroll
        for (int e = 0; e < 8; ++e) {
            a0 += we[e] * pr[0][e];
            a1 += we[e] * pr[1][e];
            a2 += we[e] * pr[2][e];
            a3 += we[e] * pr[3][e];
        }
        #pragma unroll
        for (int off = 32; off; off >>= 1) {
            a0 += __shfl_down(a0, off);
            a1 += __shfl_down(a1, off);
            a2 += __shfl_down(a2, off);
            a3 += __shfl_down(a3, off);
        }
        if (lane == 0) {
            out[0 * NOUT + j] = a0 + bias;
            out[1 * NOUT + j] = a1 + bias;
            out[2 * NOUT + j] = a2 + bias;
            out[3 * NOUT + j] = a3 + bias;
        }
    }
}

extern "C" void kernel_launch(void* const* d_in, const int* in_sizes, int n_in,
                              void* d_out, int out_size, void* d_ws, size_t ws_size,
                              hipStream_t stream) {
    const float* x     = (const float*)d_in[0];
    const float* wq    = (const float*)d_in[1];
    const float* bq    = (const float*)d_in[2];
    const float* wk    = (const float*)d_in[3];
    const float* bk    = (const float*)d_in[4];
    const float* wv    = (const float*)d_in[5];
    const float* bv    = (const float*)d_in[6];
    const float* rel_h = (const float*)d_in[7];
    const float* rel_w = (const float*)d_in[8];
    const float* w_sp  = (const float*)d_in[9];
    const float* b_sp  = (const float*)d_in[10];
    const float* w_fa  = (const float*)d_in[11];
    const float* b_fa  = (const float*)d_in[12];
    const float* w_or  = (const float*)d_in[13];
    const float* b_or  = (const float*)d_in[14];
    float* out = (float*)d_out;

    // ws: Wt bf16 | Xt bf16 | qkv bf16 | pooled f32
    short* Wt  = (short*)d_ws;                       // 3*512*256   = 393216
    short* Xt  = Wt + 393216;                        // 4*256*4096  = 4194304
    short* qkv = Xt + 4194304;                       // 4*3*512*4096= 25165824
    float* pooled = (float*)(qkv + 25165824);        // 4*512

    convert_w_kernel<<<dim3(8, 4, 3), 256, 0, stream>>>(wq, wk, wv, Wt);
    convert_x_kernel<<<dim3(8, 32, 4), 256, 0, stream>>>(x, Xt);
    qkv_mfma_kernel<<<dim3(32, 4, 12), 256, 0, stream>>>(Wt, Xt, bq, bk, bv, qkv);
    attn_pool_kernel<<<dim3(COUT, 4), 256, 0, stream>>>(
        (const unsigned short*)qkv, rel_h, rel_w, pooled);
    heads_kernel<<<dim3(2048), 256, 0, stream>>>(
        pooled, w_sp, b_sp, w_fa, b_fa, w_or, b_or, out);
}